// Round 13
// baseline (358.264 us; speedup 1.0000x reference)
//
#include <hip/hip_runtime.h>
#include <math.h>

#define NB 2048
#define NL 256
#define NH 512

typedef unsigned short ushort_t;
typedef short s16x8 __attribute__((ext_vector_type(8)));
typedef short s16x4 __attribute__((ext_vector_type(4)));
typedef float f32x4 __attribute__((ext_vector_type(4)));

__device__ __forceinline__ float wsum(float v){
  #pragma unroll
  for (int o = 32; o; o >>= 1) v += __shfl_xor(v, o);
  return v;
}
__device__ __forceinline__ float wmax(float v){
  #pragma unroll
  for (int o = 32; o; o >>= 1) v = fmaxf(v, __shfl_xor(v, o));
  return v;
}
__device__ __forceinline__ ushort_t f2bf(float f){
  union { float f; unsigned u; } v; v.f = f;
  unsigned r = v.u + 0x7fffu + ((v.u >> 16) & 1u);
  return (ushort_t)(r >> 16);
}

// ---------------------------------------------------------------------------
// kTiny (109 blocks x 256): all pre-GEMM prep (kernel-boundary-safe for
// consumers in kLogits and the mega kernel's comb tail).
//  bid <  32: WTA[c][k] = bf16 attn_W_bottom^T  (256x512)
//  bid <  96: WTC[c][k] = bf16 comb_W_bottom^T  (512x512)
//  bid < 100: p,q (attn top rank-2)
//  bid < 108: p2,q2 (comb top rank-2)
//  bid ==108: stats {mW,mb,Su2,Suv,Sv2} + zero stripe counters ctr[16]
// ---------------------------------------------------------------------------
__global__ __launch_bounds__(256)
void kTiny(const float* __restrict__ eW, const float* __restrict__ eb,
           const float* __restrict__ attn_W, const float* __restrict__ comb_W,
           ushort_t* __restrict__ WTA, ushort_t* __restrict__ WTC,
           float* __restrict__ stats,
           float* __restrict__ p, float* __restrict__ q,
           float* __restrict__ p2, float* __restrict__ q2,
           int* __restrict__ ctr)
{
  const int bid = blockIdx.x, tid = threadIdx.x;
  if (bid < 32) {                        // WTA bf16 transpose
    const int bx = bid & 3, by = bid >> 2;
    const int c = bx*64 + (tid & 63);
    const int ksub = by*64 + (tid >> 6)*16;
    ushort_t vals[16];
    #pragma unroll
    for (int kk = 0; kk < 16; ++kk)
      vals[kk] = f2bf(attn_W[(size_t)(512 + ksub + kk)*NL + c]);
    *(s16x8*)&WTA[(size_t)c*512 + ksub]     = *(s16x8*)&vals[0];
    *(s16x8*)&WTA[(size_t)c*512 + ksub + 8] = *(s16x8*)&vals[8];
    return;
  }
  if (bid < 96) {                        // WTC bf16 transpose
    const int b2 = bid - 32, bx = b2 & 7, by = b2 >> 3;
    const int c = bx*64 + (tid & 63);
    const int ksub = by*64 + (tid >> 6)*16;
    ushort_t vals[16];
    #pragma unroll
    for (int kk = 0; kk < 16; ++kk)
      vals[kk] = f2bf(comb_W[(size_t)(512 + ksub + kk)*NH + c]);
    *(s16x8*)&WTC[(size_t)c*512 + ksub]     = *(s16x8*)&vals[0];
    *(s16x8*)&WTC[(size_t)c*512 + ksub + 8] = *(s16x8*)&vals[8];
    return;
  }
  // rank-2 projections + stats
  {
    __shared__ float rw[4], rb[4];
    __shared__ float pa[4][64], pb[4][64];
    const int lane = tid & 63, wv = tid >> 6;
    float swv = eW[tid] + eW[tid + 256];
    float sbv = eb[tid] + eb[tid + 256];
    swv = wsum(swv); sbv = wsum(sbv);
    if (lane == 0) { rw[wv] = swv; rb[wv] = sbv; }
    __syncthreads();
    const float mW = (rw[0]+rw[1]+rw[2]+rw[3]) * (1.f/NH);
    const float mb = (rb[0]+rb[1]+rb[2]+rb[3]) * (1.f/NH);

    if (bid == 108) {
      if (tid < 16) ctr[tid] = 0;        // zero stripe counters for kMega
      float u0 = eW[tid]-mW, u1 = eW[tid+256]-mW;
      float v0 = eb[tid]-mb, v1 = eb[tid+256]-mb;
      float s2 = u0*u0 + u1*u1, s3 = u0*v0 + u1*v1, s4 = v0*v0 + v1*v1;
      s2 = wsum(s2); s3 = wsum(s3); s4 = wsum(s4);
      if (lane == 0) { pa[0][wv] = s2; pa[1][wv] = s3; pa[2][wv] = s4; }
      __syncthreads();
      if (tid == 0) {
        stats[0] = mW; stats[1] = mb;
        stats[2] = pa[0][0]+pa[0][1]+pa[0][2]+pa[0][3];
        stats[3] = pa[1][0]+pa[1][1]+pa[1][2]+pa[1][3];
        stats[4] = pa[2][0]+pa[2][1]+pa[2][2]+pa[2][3];
      }
      return;
    }
    const int bid2 = bid - 96;
    const float* Wsrc; int ldw, c0; float *op, *oq;
    if (bid2 < 4) { Wsrc = attn_W; ldw = NL; c0 = bid2*64;     op = p  + c0; oq = q  + c0; }
    else          { Wsrc = comb_W; ldw = NH; c0 = (bid2-4)*64; op = p2 + c0; oq = q2 + c0; }
    const int c = c0 + lane;
    const int hc = tid >> 6;
    float ap = 0.f, aq = 0.f;
    #pragma unroll 4
    for (int h = hc*128; h < hc*128 + 128; ++h) {
      float w = Wsrc[(size_t)h*ldw + c];
      ap = fmaf(eW[h]-mW, w, ap);
      aq = fmaf(eb[h]-mb, w, aq);
    }
    pa[hc][lane] = ap; pb[hc][lane] = aq;
    __syncthreads();
    if (hc == 0) {
      op[lane] = pa[0][lane]+pa[1][lane]+pa[2][lane]+pa[3][lane];
      oq[lane] = pb[0][lane]+pb[1][lane]+pb[2][lane]+pb[3][lane];
    }
  }
}

// ---------------------------------------------------------------------------
// kLogits: 128x64 tile MFMA GEMM, A staged DIRECTLY from fp32 hidden
// (cvt during staging). B = WTA bf16. Epilogue: logits = acc + attn_b + rank2
// -> fp32 [2048][256]. grid(16,4).
// ---------------------------------------------------------------------------
__global__ __launch_bounds__(256)
void kLogits(const float* __restrict__ hidden, const ushort_t* __restrict__ WTA,
             const float* __restrict__ x, const float* __restrict__ stats,
             const float* __restrict__ p, const float* __restrict__ q,
             const float* __restrict__ attn_b, float* __restrict__ logits)
{
  __shared__ ushort_t As[128][72];
  __shared__ ushort_t Bs[64][72];
  const int tid = threadIdx.x, lane = tid & 63, wr = tid >> 6;
  const int m0 = blockIdx.x * 128, n0 = blockIdx.y * 64;

  f32x4 acc[2][4];
  #pragma unroll
  for (int i = 0; i < 2; ++i)
    #pragma unroll
    for (int j = 0; j < 4; ++j)
      acc[i][j] = (f32x4){0.f,0.f,0.f,0.f};

  const int srow = tid >> 3, scol = (tid & 7) * 8;
  for (int kt = 0; kt < 512; kt += 64) {
    __syncthreads();
    #pragma unroll
    for (int it = 0; it < 4; ++it) {
      const int r = srow + it*32;
      const float* hp = hidden + (size_t)(m0+r)*NH + kt + scol;
      float4 v0 = *(const float4*)hp;
      float4 v1 = *(const float4*)(hp + 4);
      s16x8 o;
      o[0]=f2bf(v0.x); o[1]=f2bf(v0.y); o[2]=f2bf(v0.z); o[3]=f2bf(v0.w);
      o[4]=f2bf(v1.x); o[5]=f2bf(v1.y); o[6]=f2bf(v1.z); o[7]=f2bf(v1.w);
      *(s16x8*)&As[r][scol] = o;
    }
    #pragma unroll
    for (int it = 0; it < 2; ++it) {
      const int r = srow + it*32;
      *(s16x8*)&Bs[r][scol] = *(const s16x8*)&WTA[(size_t)(n0+r)*512 + kt + scol];
    }
    __syncthreads();
    #pragma unroll
    for (int ks = 0; ks < 2; ++ks) {
      const int ko = ks*32 + (lane >> 4)*8;
      s16x8 af[2], bfr[4];
      #pragma unroll
      for (int i = 0; i < 2; ++i) af[i]  = *(const s16x8*)&As[wr*32 + i*16 + (lane & 15)][ko];
      #pragma unroll
      for (int j = 0; j < 4; ++j) bfr[j] = *(const s16x8*)&Bs[j*16 + (lane & 15)][ko];
      #pragma unroll
      for (int i = 0; i < 2; ++i)
        #pragma unroll
        for (int j = 0; j < 4; ++j)
          acc[i][j] = __builtin_amdgcn_mfma_f32_16x16x32_bf16(af[i], bfr[j], acc[i][j], 0, 0, 0);
    }
  }

  const float S2 = stats[2], S3 = stats[3], S4 = stats[4];
  #pragma unroll
  for (int i = 0; i < 2; ++i) {
    #pragma unroll
    for (int reg = 0; reg < 4; ++reg) {
      const int row = m0 + wr*32 + i*16 + ((lane >> 4) << 2) + reg;
      const float xv = x[row];
      const float rs = rsqrtf((xv*xv*S2 + 2.f*xv*S3 + S4)*(1.0f/NH) + 1e-5f);
      const float al = xv*rs, be = rs;
      #pragma unroll
      for (int j = 0; j < 4; ++j) {
        const int col = n0 + j*16 + (lane & 15);
        logits[(size_t)row*NL + col] = acc[i][j][reg] + attn_b[col] + al*p[col] + be*q[col];
      }
    }
  }
}

// ---------------------------------------------------------------------------
// kMega (3208 blocks x 256): stream + prep + producer-consumer comb tail.
//  bid < 2048: stream block b: softmax(logits[b]) -> attn_out + wl; then
//       a = sum_l wl*enc[b] -> bf16 ABF; syncthreads; threadfence;
//       atomicAdd(ctr[b>>7]) — signals the 128-row stripe.
//  bid < 2560: hidden fp32 -> bf16 into A2 right half (lda 1024)
//  bid < 3072: WTG[n][k] bf16 gate-interleaved blockdiag GRU weight
//  bid < 3080: out0[b] = out_b[0]
//  else (128 blocks): comb tile (m0,n0): spin until ctr[stripe]==128, then
//       xt = relu(ABF @ WTC^T + comb_b + rank2) -> bf16 A2 left. Dispatch
//       order guarantees all stream blocks are scheduled before any comb
//       block gets a CU slot (comb idx>=3080, capacity ~1280) — no deadlock.
// ---------------------------------------------------------------------------
__global__ __launch_bounds__(256)
void kMega(const float* __restrict__ hidden,
           const float* __restrict__ Wih, const float* __restrict__ Whh,
           const float* __restrict__ out_b,
           const float* __restrict__ logits, const float* __restrict__ enc,
           const ushort_t* __restrict__ WTC,
           const float* __restrict__ x, const float* __restrict__ stats,
           const float* __restrict__ p2, const float* __restrict__ q2,
           const float* __restrict__ comb_b,
           ushort_t* __restrict__ A2, ushort_t* __restrict__ WTG,
           float* __restrict__ out0, int* __restrict__ ctr,
           float* __restrict__ attn_out, ushort_t* __restrict__ ABF)
{
  const int bid = blockIdx.x, tid = threadIdx.x;
  if (bid < 2048) {                      // ---- stream block
    __shared__ float wl[NL];
    __shared__ __align__(16) float4 ps[128];
    __shared__ float sred[4];
    const int lane = tid & 63, wv = tid >> 6;
    const int b = bid;

    float lg = logits[(size_t)b*NL + tid];
    float m = wmax(lg);
    if (lane == 0) sred[wv] = m;
    __syncthreads();
    m = fmaxf(fmaxf(sred[0], sred[1]), fmaxf(sred[2], sred[3]));
    float e = expf(lg - m);
    float s = wsum(e);
    __syncthreads();
    if (lane == 0) sred[wv] = s;
    __syncthreads();
    const float inv = 1.f / (sred[0] + sred[1] + sred[2] + sred[3]);
    e *= inv;
    wl[tid] = e;
    attn_out[(size_t)b*NL + tid] = e;
    __syncthreads();

    const int col = tid & 127, half = tid >> 7;
    const f32x4* ep = (const f32x4*)(enc + (size_t)b*NL*NH);
    float4 acc = {0.f,0.f,0.f,0.f};
    #pragma unroll 4
    for (int l = half*128; l < half*128 + 128; ++l) {
      float w = wl[l];
      f32x4 ev = __builtin_nontemporal_load(ep + l*(NH/4) + col);
      acc.x = fmaf(w,ev[0],acc.x); acc.y = fmaf(w,ev[1],acc.y);
      acc.z = fmaf(w,ev[2],acc.z); acc.w = fmaf(w,ev[3],acc.w);
    }
    if (half == 0) ps[col] = acc;
    __syncthreads();
    if (half == 1) {
      float4 o = ps[col];
      o.x += acc.x; o.y += acc.y; o.z += acc.z; o.w += acc.w;
      s16x4 ov; ov[0]=f2bf(o.x); ov[1]=f2bf(o.y); ov[2]=f2bf(o.z); ov[3]=f2bf(o.w);
      *(s16x4*)&ABF[(size_t)b*NH + col*4] = ov;
    }
    __syncthreads();                     // drain all threads' ABF stores
    if (tid == 0) {
      __threadfence();                   // device-visible before signal
      atomicAdd(&ctr[b >> 7], 1);
    }
    return;
  }
  if (bid < 2560) {                      // hidden -> bf16 A2 right half
    const int idx = ((bid-2048)*256 + tid) * 8;
    const int b = idx >> 9, h = idx & 511;
    float4 v0 = *(const float4*)(hidden + idx);
    float4 v1 = *(const float4*)(hidden + idx + 4);
    s16x8 o;
    o[0]=f2bf(v0.x); o[1]=f2bf(v0.y); o[2]=f2bf(v0.z); o[3]=f2bf(v0.w);
    o[4]=f2bf(v1.x); o[5]=f2bf(v1.y); o[6]=f2bf(v1.z); o[7]=f2bf(v1.w);
    *(s16x8*)&A2[(size_t)b*1024 + 512 + h] = o;
    return;
  }
  if (bid < 3072) {                      // WTG bf16 gate-blockdiag
    const int b2 = bid - 2560, bx = b2 & 31, by = b2 >> 5;
    const int n = bx*64 + (tid & 63);
    const int ksub = by*64 + (tid >> 6)*16;
    const int g = n >> 6, t = (n >> 4) & 3, c = (g << 4) | (n & 15);
    const int sc = (t == 0) ? c : (t == 1) ? (512 + c) : (1024 + c);
    ushort_t vals[16];
    #pragma unroll
    for (int kk = 0; kk < 16; ++kk) {
      int k = ksub + kk;
      float v;
      if (k < 512) v = (t == 3) ? 0.f : Wih[(size_t)k*1536 + sc];
      else         v = (t == 2) ? 0.f : Whh[(size_t)(k-512)*1536 + sc];
      vals[kk] = f2bf(v);
    }
    *(s16x8*)&WTG[(size_t)n*1024 + ksub]     = *(s16x8*)&vals[0];
    *(s16x8*)&WTG[(size_t)n*1024 + ksub + 8] = *(s16x8*)&vals[8];
    return;
  }
  if (bid < 3080) {                      // out0 init
    out0[(bid-3072)*256 + tid] = out_b[0];
    return;
  }
  // ---- comb tail block: spin on stripe, then MFMA comb GEMM
  {
    __shared__ ushort_t As[128][72];
    __shared__ ushort_t Bs[64][72];
    const int b2 = bid - 3080;
    const int m0 = (b2 >> 3) * 128, n0 = (b2 & 7) * 64;
    const int lane = tid & 63, wr = tid >> 6;

    if (tid == 0) {
      while (atomicAdd(&ctr[m0 >> 7], 0) < 128) __builtin_amdgcn_s_sleep(32);
    }
    __syncthreads();
    __threadfence();                     // acquire side

    f32x4 acc[2][4];
    #pragma unroll
    for (int i = 0; i < 2; ++i)
      #pragma unroll
      for (int j = 0; j < 4; ++j)
        acc[i][j] = (f32x4){0.f,0.f,0.f,0.f};

    const int srow = tid >> 3, scol = (tid & 7) * 8;
    for (int kt = 0; kt < 512; kt += 64) {
      __syncthreads();
      #pragma unroll
      for (int it = 0; it < 4; ++it) {
        const int r = srow + it*32;
        *(s16x8*)&As[r][scol] = *(const s16x8*)&ABF[(size_t)(m0+r)*512 + kt + scol];
      }
      #pragma unroll
      for (int it = 0; it < 2; ++it) {
        const int r = srow + it*32;
        *(s16x8*)&Bs[r][scol] = *(const s16x8*)&WTC[(size_t)(n0+r)*512 + kt + scol];
      }
      __syncthreads();
      #pragma unroll
      for (int ks = 0; ks < 2; ++ks) {
        const int ko = ks*32 + (lane >> 4)*8;
        s16x8 af[2], bfr[4];
        #pragma unroll
        for (int i = 0; i < 2; ++i) af[i]  = *(const s16x8*)&As[wr*32 + i*16 + (lane & 15)][ko];
        #pragma unroll
        for (int j = 0; j < 4; ++j) bfr[j] = *(const s16x8*)&Bs[j*16 + (lane & 15)][ko];
        #pragma unroll
        for (int i = 0; i < 2; ++i)
          #pragma unroll
          for (int j = 0; j < 4; ++j)
            acc[i][j] = __builtin_amdgcn_mfma_f32_16x16x32_bf16(af[i], bfr[j], acc[i][j], 0, 0, 0);
      }
    }

    const float S2 = stats[2], S3 = stats[3], S4 = stats[4];
    #pragma unroll
    for (int i = 0; i < 2; ++i) {
      #pragma unroll
      for (int reg = 0; reg < 4; ++reg) {
        const int row = m0 + wr*32 + i*16 + ((lane >> 4) << 2) + reg;
        const float xv = x[row];
        const float rs = rsqrtf((xv*xv*S2 + 2.f*xv*S3 + S4)*(1.0f/NH) + 1e-5f);
        const float al = xv*rs, be = rs;
        #pragma unroll
        for (int j = 0; j < 4; ++j) {
          const int col = n0 + j*16 + (lane & 15);
          float v = acc[i][j][reg] + comb_b[col] + al*p2[col] + be*q2[col];
          A2[(size_t)row*1024 + col] = f2bf(fmaxf(v, 0.f));
        }
      }
    }
  }
}

// ---------------------------------------------------------------------------
// kGRU: 128x64 tile, 4 waves (4x1), 512 blocks = 2/CU. Block-diagonal skip
// (12 MFMAs/K-step; zero B rows unstaged). Epilogue: GRU gates -> h_new fp32
// + fused out0 atomic reduce (out0 pre-init in kMega).
// ---------------------------------------------------------------------------
__global__ __launch_bounds__(256)
void kGRU(const ushort_t* __restrict__ A, const ushort_t* __restrict__ Bt,
          const float* __restrict__ bih, const float* __restrict__ bhh,
          const float* __restrict__ hidden, const float* __restrict__ out_W,
          float* __restrict__ h_out, float* __restrict__ out0)
{
  __shared__ ushort_t As[128][72];
  __shared__ ushort_t Bs[64][72];
  const int tid = threadIdx.x, lane = tid & 63, wr = tid >> 6;
  const int m0 = blockIdx.x * 128, n0 = blockIdx.y * 64;

  f32x4 acc[2][4];
  #pragma unroll
  for (int i = 0; i < 2; ++i)
    #pragma unroll
    for (int j = 0; j < 4; ++j)
      acc[i][j] = (f32x4){0.f,0.f,0.f,0.f};

  const int srow = tid >> 3, scol = (tid & 7) * 8;

  // ---- K half 1: k in [0,512), active gates j = 0,1,2 (B rows t==3 zero)
  for (int kt = 0; kt < 512; kt += 64) {
    __syncthreads();
    #pragma unroll
    for (int it = 0; it < 4; ++it) {
      const int r = srow + it*32;
      *(s16x8*)&As[r][scol] = *(const s16x8*)&A[(size_t)(m0+r)*1024 + kt + scol];
    }
    {
      *(s16x8*)&Bs[srow][scol] = *(const s16x8*)&Bt[(size_t)(n0+srow)*1024 + kt + scol];
      if (srow < 16) {
        const int r = srow + 32;
        *(s16x8*)&Bs[r][scol] = *(const s16x8*)&Bt[(size_t)(n0+r)*1024 + kt + scol];
      }
    }
    __syncthreads();
    #pragma unroll
    for (int ks = 0; ks < 2; ++ks) {
      const int ko = ks*32 + (lane >> 4)*8;
      s16x8 af[2], b0, b1, b2;
      #pragma unroll
      for (int i = 0; i < 2; ++i) af[i] = *(const s16x8*)&As[wr*32 + i*16 + (lane & 15)][ko];
      b0 = *(const s16x8*)&Bs[0*16 + (lane & 15)][ko];
      b1 = *(const s16x8*)&Bs[1*16 + (lane & 15)][ko];
      b2 = *(const s16x8*)&Bs[2*16 + (lane & 15)][ko];
      #pragma unroll
      for (int i = 0; i < 2; ++i) {
        acc[i][0] = __builtin_amdgcn_mfma_f32_16x16x32_bf16(af[i], b0, acc[i][0], 0, 0, 0);
        acc[i][1] = __builtin_amdgcn_mfma_f32_16x16x32_bf16(af[i], b1, acc[i][1], 0, 0, 0);
        acc[i][2] = __builtin_amdgcn_mfma_f32_16x16x32_bf16(af[i], b2, acc[i][2], 0, 0, 0);
      }
    }
  }
  // ---- K half 2: k in [512,1024), active gates j = 0,1,3 (B rows t==2 zero)
  for (int kt = 512; kt < 1024; kt += 64) {
    __syncthreads();
    #pragma unroll
    for (int it = 0; it < 4; ++it) {
      const int r = srow + it*32;
      *(s16x8*)&As[r][scol] = *(const s16x8*)&A[(size_t)(m0+r)*1024 + kt + scol];
    }
    {
      *(s16x8*)&Bs[srow][scol] = *(const s16x8*)&Bt[(size_t)(n0+srow)*1024 + kt + scol];
      if (srow >= 16) {
        const int r = srow + 32;
        *(s16x8*)&Bs[r][scol] = *(const s16x8*)&Bt[(size_t)(n0+r)*1024 + kt + scol];
      }
    }
    __syncthreads();
    #pragma unroll
    for (int ks = 0; ks < 2; ++ks) {
      const int ko = ks*32 + (lane >> 4)*8;
      s16x8 af[2], b0, b1, b3;
      #pragma unroll
      for (int i = 0; i < 2; ++i) af[i] = *(const s16x8*)&As[wr*32 + i*16 + (lane & 15)][ko];
      b0 = *(const s16x8*)&Bs[0*16 + (lane & 15)][ko];
      b1 = *(const s16x8*)&Bs[1*16 + (lane & 15)][ko];
      b3 = *(const s16x8*)&Bs[3*16 + (lane & 15)][ko];
      #pragma unroll
      for (int i = 0; i < 2; ++i) {
        acc[i][0] = __builtin_amdgcn_mfma_f32_16x16x32_bf16(af[i], b0, acc[i][0], 0, 0, 0);
        acc[i][1] = __builtin_amdgcn_mfma_f32_16x16x32_bf16(af[i], b1, acc[i][1], 0, 0, 0);
        acc[i][3] = __builtin_amdgcn_mfma_f32_16x16x32_bf16(af[i], b3, acc[i][3], 0, 0, 0);
      }
    }
  }

  const int g = n0 >> 6;
  const int hcol = (g << 4) | (lane & 15);
  const float b_r = bih[hcol]        + bhh[hcol];
  const float b_z = bih[512 + hcol]  + bhh[512 + hcol];
  const float b_i = bih[1024 + hcol];
  const float b_h = bhh[1024 + hcol];
  const float ow  = out_W[hcol];
  #pragma unroll
  for (int i = 0; i < 2; ++i) {
    #pragma unroll
    for (int reg = 0; reg < 4; ++reg) {
      const int row = m0 + wr*32 + i*16 + ((lane >> 4) << 2) + reg;
      float rv = 1.f / (1.f + expf(-(acc[i][0][reg] + b_r)));
      float zv = 1.f / (1.f + expf(-(acc[i][1][reg] + b_z)));
      float nv = tanhf(acc[i][2][reg] + b_i + rv * (acc[i][3][reg] + b_h));
      float h0v = hidden[(size_t)row*NH + hcol];
      float hn = nv + zv * (h0v - nv);
      h_out[(size_t)row*NH + hcol] = hn;
      float partial = hn * ow;
      #pragma unroll
      for (int o = 1; o < 16; o <<= 1) partial += __shfl_xor(partial, o);
      if ((lane & 15) == 0) atomicAdd(&out0[row], partial);
    }
  }
}

// ---------------------------------------------------------------------------
extern "C" void kernel_launch(void* const* d_in, const int* in_sizes, int n_in,
                              void* d_out, int out_size, void* d_ws, size_t ws_size,
                              hipStream_t stream)
{
  const float* x      = (const float*)d_in[0];
  const float* hidden = (const float*)d_in[1];
  const float* enc    = (const float*)d_in[2];
  const float* emb_W  = (const float*)d_in[3];
  const float* emb_b  = (const float*)d_in[4];
  const float* attn_W = (const float*)d_in[5];
  const float* attn_b = (const float*)d_in[6];
  const float* comb_W = (const float*)d_in[7];
  const float* comb_b = (const float*)d_in[8];
  const float* Wih    = (const float*)d_in[9];
  const float* Whh    = (const float*)d_in[10];
  const float* bih    = (const float*)d_in[11];
  const float* bhh    = (const float*)d_in[12];
  const float* out_W  = (const float*)d_in[13];
  const float* out_b  = (const float*)d_in[14];

  float* out      = (float*)d_out;
  float* out0     = out;                          // 2048
  float* out_h    = out + NB;                     // B*H
  float* out_attn = out + NB + (size_t)NB*NH;     // B*L

  float* wsf    = (float*)d_ws;
  int*   ctr    = (int*)wsf;        // 16 stripe counters
  float* stats  = wsf + 16;         // 5
  float* p      = wsf + 32;         // 256
  float* q      = wsf + 288;        // 256
  float* p2     = wsf + 544;        // 512
  float* q2     = wsf + 1056;       // 512
  float* logits = wsf + 2048;       // [2048][256] fp32
  ushort_t* usb = (ushort_t*)(wsf + 526400);
  ushort_t* A2  = usb;              // [2048][1024] bf16: [xt | h0]
  ushort_t* ABF = usb + 2097152;    // [2048][512]  bf16 attn_applied
  ushort_t* WTA = usb + 3145728;    // [256][512]
  ushort_t* WTC = usb + 3276800;    // [512][512]
  ushort_t* WTG = usb + 3538944;    // [2048][1024]

  kTiny<<<109, 256, 0, stream>>>(emb_W, emb_b, attn_W, comb_W,
                                 WTA, WTC, stats, p, q, p2, q2, ctr);
  kLogits<<<dim3(16, 4), 256, 0, stream>>>(hidden, WTA, x, stats, p, q,
                                           attn_b, logits);
  kMega<<<3208, 256, 0, stream>>>(hidden, Wih, Whh, out_b, logits, enc,
                                  WTC, x, stats, p2, q2, comb_b,
                                  A2, WTG, out0, ctr, out_attn, ABF);
  kGRU<<<dim3(16, 32), 256, 0, stream>>>(A2, WTG, bih, bhh, hidden, out_W,
                                         out_h, out0);
}

// Round 14
// 264.868 us; speedup vs baseline: 1.3526x; 1.3526x over previous
//
#include <hip/hip_runtime.h>
#include <math.h>

#define NB 2048
#define NL 256
#define NH 512

typedef unsigned short ushort_t;
typedef short s16x8 __attribute__((ext_vector_type(8)));
typedef short s16x4 __attribute__((ext_vector_type(4)));
typedef float f32x4 __attribute__((ext_vector_type(4)));

__device__ __forceinline__ float wsum(float v){
  #pragma unroll
  for (int o = 32; o; o >>= 1) v += __shfl_xor(v, o);
  return v;
}
__device__ __forceinline__ float wmax(float v){
  #pragma unroll
  for (int o = 32; o; o >>= 1) v = fmaxf(v, __shfl_xor(v, o));
  return v;
}
__device__ __forceinline__ ushort_t f2bf(float f){
  union { float f; unsigned u; } v; v.f = f;
  unsigned r = v.u + 0x7fffu + ((v.u >> 16) & 1u);
  return (ushort_t)(r >> 16);
}

// ---------------------------------------------------------------------------
// kTiny (37 blocks x 256): minimal pre-logits prep (r12-proven).
//  bid < 32: WTA[c][k] = bf16 attn_W_bottom^T  (256x512)
//  bid < 36: p,q (attn top rank-2)
//  bid ==36: stats = {mW, mb, Su2, Suv, Sv2}
// ---------------------------------------------------------------------------
__global__ __launch_bounds__(256)
void kTiny(const float* __restrict__ eW, const float* __restrict__ eb,
           const float* __restrict__ attn_W,
           ushort_t* __restrict__ WTA, float* __restrict__ stats,
           float* __restrict__ p, float* __restrict__ q)
{
  const int bid = blockIdx.x, tid = threadIdx.x;
  if (bid < 32) {                        // WTA bf16 transpose
    const int bx = bid & 3, by = bid >> 2;
    const int c = bx*64 + (tid & 63);
    const int ksub = by*64 + (tid >> 6)*16;
    ushort_t vals[16];
    #pragma unroll
    for (int kk = 0; kk < 16; ++kk)
      vals[kk] = f2bf(attn_W[(size_t)(512 + ksub + kk)*NL + c]);
    *(s16x8*)&WTA[(size_t)c*512 + ksub]     = *(s16x8*)&vals[0];
    *(s16x8*)&WTA[(size_t)c*512 + ksub + 8] = *(s16x8*)&vals[8];
    return;
  }
  // rank-2 projections + stats
  {
    __shared__ float rw[4], rb[4];
    __shared__ float pa[4][64], pb[4][64];
    const int lane = tid & 63, wv = tid >> 6;
    float swv = eW[tid] + eW[tid + 256];
    float sbv = eb[tid] + eb[tid + 256];
    swv = wsum(swv); sbv = wsum(sbv);
    if (lane == 0) { rw[wv] = swv; rb[wv] = sbv; }
    __syncthreads();
    const float mW = (rw[0]+rw[1]+rw[2]+rw[3]) * (1.f/NH);
    const float mb = (rb[0]+rb[1]+rb[2]+rb[3]) * (1.f/NH);

    if (bid == 36) {
      float u0 = eW[tid]-mW, u1 = eW[tid+256]-mW;
      float v0 = eb[tid]-mb, v1 = eb[tid+256]-mb;
      float s2 = u0*u0 + u1*u1, s3 = u0*v0 + u1*v1, s4 = v0*v0 + v1*v1;
      s2 = wsum(s2); s3 = wsum(s3); s4 = wsum(s4);
      if (lane == 0) { pa[0][wv] = s2; pa[1][wv] = s3; pa[2][wv] = s4; }
      __syncthreads();
      if (tid == 0) {
        stats[0] = mW; stats[1] = mb;
        stats[2] = pa[0][0]+pa[0][1]+pa[0][2]+pa[0][3];
        stats[3] = pa[1][0]+pa[1][1]+pa[1][2]+pa[1][3];
        stats[4] = pa[2][0]+pa[2][1]+pa[2][2]+pa[2][3];
      }
      return;
    }
    const int c = (bid - 32)*64 + lane;
    const int hc = tid >> 6;
    float ap = 0.f, aq = 0.f;
    #pragma unroll 4
    for (int h = hc*128; h < hc*128 + 128; ++h) {
      float w = attn_W[(size_t)h*NL + c];
      ap = fmaf(eW[h]-mW, w, ap);
      aq = fmaf(eb[h]-mb, w, aq);
    }
    pa[hc][lane] = ap; pb[hc][lane] = aq;
    __syncthreads();
    if (hc == 0) {
      p[c] = pa[0][lane]+pa[1][lane]+pa[2][lane]+pa[3][lane];
      q[c] = pb[0][lane]+pb[1][lane]+pb[2][lane]+pb[3][lane];
    }
  }
}

// ---------------------------------------------------------------------------
// kLogits: 128x64 tile MFMA GEMM, A staged DIRECTLY from fp32 hidden
// (cvt during staging). B = WTA bf16. Epilogue: logits = acc + attn_b + rank2
// -> fp32 [2048][256]. grid(16,4).
// ---------------------------------------------------------------------------
__global__ __launch_bounds__(256)
void kLogits(const float* __restrict__ hidden, const ushort_t* __restrict__ WTA,
             const float* __restrict__ x, const float* __restrict__ stats,
             const float* __restrict__ p, const float* __restrict__ q,
             const float* __restrict__ attn_b, float* __restrict__ logits)
{
  __shared__ ushort_t As[128][72];
  __shared__ ushort_t Bs[64][72];
  const int tid = threadIdx.x, lane = tid & 63, wr = tid >> 6;
  const int m0 = blockIdx.x * 128, n0 = blockIdx.y * 64;

  f32x4 acc[2][4];
  #pragma unroll
  for (int i = 0; i < 2; ++i)
    #pragma unroll
    for (int j = 0; j < 4; ++j)
      acc[i][j] = (f32x4){0.f,0.f,0.f,0.f};

  const int srow = tid >> 3, scol = (tid & 7) * 8;
  for (int kt = 0; kt < 512; kt += 64) {
    __syncthreads();
    #pragma unroll
    for (int it = 0; it < 4; ++it) {
      const int r = srow + it*32;
      const float* hp = hidden + (size_t)(m0+r)*NH + kt + scol;
      float4 v0 = *(const float4*)hp;
      float4 v1 = *(const float4*)(hp + 4);
      s16x8 o;
      o[0]=f2bf(v0.x); o[1]=f2bf(v0.y); o[2]=f2bf(v0.z); o[3]=f2bf(v0.w);
      o[4]=f2bf(v1.x); o[5]=f2bf(v1.y); o[6]=f2bf(v1.z); o[7]=f2bf(v1.w);
      *(s16x8*)&As[r][scol] = o;
    }
    #pragma unroll
    for (int it = 0; it < 2; ++it) {
      const int r = srow + it*32;
      *(s16x8*)&Bs[r][scol] = *(const s16x8*)&WTA[(size_t)(n0+r)*512 + kt + scol];
    }
    __syncthreads();
    #pragma unroll
    for (int ks = 0; ks < 2; ++ks) {
      const int ko = ks*32 + (lane >> 4)*8;
      s16x8 af[2], bfr[4];
      #pragma unroll
      for (int i = 0; i < 2; ++i) af[i]  = *(const s16x8*)&As[wr*32 + i*16 + (lane & 15)][ko];
      #pragma unroll
      for (int j = 0; j < 4; ++j) bfr[j] = *(const s16x8*)&Bs[j*16 + (lane & 15)][ko];
      #pragma unroll
      for (int i = 0; i < 2; ++i)
        #pragma unroll
        for (int j = 0; j < 4; ++j)
          acc[i][j] = __builtin_amdgcn_mfma_f32_16x16x32_bf16(af[i], bfr[j], acc[i][j], 0, 0, 0);
    }
  }

  const float S2 = stats[2], S3 = stats[3], S4 = stats[4];
  #pragma unroll
  for (int i = 0; i < 2; ++i) {
    #pragma unroll
    for (int reg = 0; reg < 4; ++reg) {
      const int row = m0 + wr*32 + i*16 + ((lane >> 4) << 2) + reg;
      const float xv = x[row];
      const float rs = rsqrtf((xv*xv*S2 + 2.f*xv*S3 + S4)*(1.0f/NH) + 1e-5f);
      const float al = xv*rs, be = rs;
      #pragma unroll
      for (int j = 0; j < 4; ++j) {
        const int col = n0 + j*16 + (lane & 15);
        logits[(size_t)row*NL + col] = acc[i][j][reg] + attn_b[col] + al*p[col] + be*q[col];
      }
    }
  }
}

// ---------------------------------------------------------------------------
// kStreamMega (3152 blocks x 256): STREAM BLOCKS FIRST (bid < 2048); prep
// blocks dispatch into the stream's spare slots as stream blocks retire.
//  bid < 2048: softmax(logits[b]) -> attn_out + wl; a = sum_l wl*enc -> ABF
//  bid < 2560: hidden fp32 -> bf16 into A2 right half (lda 1024)
//  bid < 3072: WTG[n][k] bf16 gate-interleaved blockdiag GRU weight
//  bid < 3136: WTC[c][k] = bf16 comb_W_bottom^T (512x512)
//  bid < 3144: p2,q2 (comb top rank-2)
//  else      : out0[b] = out_b[0]
// ---------------------------------------------------------------------------
__global__ __launch_bounds__(256)
void kStreamMega(const float* __restrict__ hidden,
                 const float* __restrict__ Wih, const float* __restrict__ Whh,
                 const float* __restrict__ comb_W,
                 const float* __restrict__ eW, const float* __restrict__ eb,
                 const float* __restrict__ out_b,
                 const float* __restrict__ logits, const float* __restrict__ enc,
                 ushort_t* __restrict__ A2, ushort_t* __restrict__ WTG,
                 ushort_t* __restrict__ WTC,
                 float* __restrict__ p2, float* __restrict__ q2,
                 float* __restrict__ out0,
                 float* __restrict__ attn_out, ushort_t* __restrict__ ABF)
{
  const int bid = blockIdx.x, tid = threadIdx.x;
  if (bid < 2048) {                      // ---- stream block
    __shared__ float wl[NL];
    __shared__ __align__(16) float4 ps[128];
    __shared__ float sred[4];
    const int lane = tid & 63, wv = tid >> 6;
    const int b = bid;

    float lg = logits[(size_t)b*NL + tid];
    float m = wmax(lg);
    if (lane == 0) sred[wv] = m;
    __syncthreads();
    m = fmaxf(fmaxf(sred[0], sred[1]), fmaxf(sred[2], sred[3]));
    float e = expf(lg - m);
    float s = wsum(e);
    __syncthreads();
    if (lane == 0) sred[wv] = s;
    __syncthreads();
    const float inv = 1.f / (sred[0] + sred[1] + sred[2] + sred[3]);
    e *= inv;
    wl[tid] = e;
    attn_out[(size_t)b*NL + tid] = e;
    __syncthreads();

    const int col = tid & 127, half = tid >> 7;
    const f32x4* ep = (const f32x4*)(enc + (size_t)b*NL*NH);
    float4 acc = {0.f,0.f,0.f,0.f};
    #pragma unroll 4
    for (int l = half*128; l < half*128 + 128; ++l) {
      float w = wl[l];
      f32x4 ev = __builtin_nontemporal_load(ep + l*(NH/4) + col);
      acc.x = fmaf(w,ev[0],acc.x); acc.y = fmaf(w,ev[1],acc.y);
      acc.z = fmaf(w,ev[2],acc.z); acc.w = fmaf(w,ev[3],acc.w);
    }
    if (half == 0) ps[col] = acc;
    __syncthreads();
    if (half == 1) {
      float4 o = ps[col];
      o.x += acc.x; o.y += acc.y; o.z += acc.z; o.w += acc.w;
      s16x4 ov; ov[0]=f2bf(o.x); ov[1]=f2bf(o.y); ov[2]=f2bf(o.z); ov[3]=f2bf(o.w);
      *(s16x4*)&ABF[(size_t)b*NH + col*4] = ov;
    }
    return;
  }
  if (bid < 2560) {                      // hidden -> bf16 A2 right half
    const int idx = ((bid-2048)*256 + tid) * 8;
    const int b = idx >> 9, h = idx & 511;
    float4 v0 = *(const float4*)(hidden + idx);
    float4 v1 = *(const float4*)(hidden + idx + 4);
    s16x8 o;
    o[0]=f2bf(v0.x); o[1]=f2bf(v0.y); o[2]=f2bf(v0.z); o[3]=f2bf(v0.w);
    o[4]=f2bf(v1.x); o[5]=f2bf(v1.y); o[6]=f2bf(v1.z); o[7]=f2bf(v1.w);
    *(s16x8*)&A2[(size_t)b*1024 + 512 + h] = o;
    return;
  }
  if (bid < 3072) {                      // WTG bf16 gate-blockdiag
    const int b2 = bid - 2560, bx = b2 & 31, by = b2 >> 5;
    const int n = bx*64 + (tid & 63);
    const int ksub = by*64 + (tid >> 6)*16;
    const int g = n >> 6, t = (n >> 4) & 3, c = (g << 4) | (n & 15);
    const int sc = (t == 0) ? c : (t == 1) ? (512 + c) : (1024 + c);
    ushort_t vals[16];
    #pragma unroll
    for (int kk = 0; kk < 16; ++kk) {
      int k = ksub + kk;
      float v;
      if (k < 512) v = (t == 3) ? 0.f : Wih[(size_t)k*1536 + sc];
      else         v = (t == 2) ? 0.f : Whh[(size_t)(k-512)*1536 + sc];
      vals[kk] = f2bf(v);
    }
    *(s16x8*)&WTG[(size_t)n*1024 + ksub]     = *(s16x8*)&vals[0];
    *(s16x8*)&WTG[(size_t)n*1024 + ksub + 8] = *(s16x8*)&vals[8];
    return;
  }
  if (bid < 3136) {                      // WTC bf16 transpose
    const int b2 = bid - 3072, bx = b2 & 7, by = b2 >> 3;
    const int c = bx*64 + (tid & 63);
    const int ksub = by*64 + (tid >> 6)*16;
    ushort_t vals[16];
    #pragma unroll
    for (int kk = 0; kk < 16; ++kk)
      vals[kk] = f2bf(comb_W[(size_t)(512 + ksub + kk)*NH + c]);
    *(s16x8*)&WTC[(size_t)c*512 + ksub]     = *(s16x8*)&vals[0];
    *(s16x8*)&WTC[(size_t)c*512 + ksub + 8] = *(s16x8*)&vals[8];
    return;
  }
  if (bid < 3144) {                      // p2,q2 (comb top rank-2)
    __shared__ float rw[4], rb[4];
    __shared__ float pa[4][64], pb[4][64];
    const int lane = tid & 63, wv = tid >> 6;
    float swv = eW[tid] + eW[tid + 256];
    float sbv = eb[tid] + eb[tid + 256];
    swv = wsum(swv); sbv = wsum(sbv);
    if (lane == 0) { rw[wv] = swv; rb[wv] = sbv; }
    __syncthreads();
    const float mW = (rw[0]+rw[1]+rw[2]+rw[3]) * (1.f/NH);
    const float mb = (rb[0]+rb[1]+rb[2]+rb[3]) * (1.f/NH);
    const int c = (bid - 3136)*64 + lane;
    const int hc = tid >> 6;
    float ap = 0.f, aq = 0.f;
    #pragma unroll 4
    for (int h = hc*128; h < hc*128 + 128; ++h) {
      float w = comb_W[(size_t)h*NH + c];
      ap = fmaf(eW[h]-mW, w, ap);
      aq = fmaf(eb[h]-mb, w, aq);
    }
    pa[hc][lane] = ap; pb[hc][lane] = aq;
    __syncthreads();
    if (hc == 0) {
      p2[c] = pa[0][lane]+pa[1][lane]+pa[2][lane]+pa[3][lane];
      q2[c] = pb[0][lane]+pb[1][lane]+pb[2][lane]+pb[3][lane];
    }
    return;
  }
  out0[(bid-3144)*256 + tid] = out_b[0]; // out0 init
}

// ---------------------------------------------------------------------------
// kComb: 128x64 tile. xt = relu(ABF @ WTC^T + comb_b + rank2) -> bf16 A2 left
// (ld 1024). grid(16,8).
// ---------------------------------------------------------------------------
__global__ __launch_bounds__(256)
void kComb(const ushort_t* __restrict__ ABF, const ushort_t* __restrict__ WTC,
           const float* __restrict__ x, const float* __restrict__ stats,
           const float* __restrict__ p2, const float* __restrict__ q2,
           const float* __restrict__ comb_b, ushort_t* __restrict__ A2)
{
  __shared__ ushort_t As[128][72];
  __shared__ ushort_t Bs[64][72];
  const int tid = threadIdx.x, lane = tid & 63, wr = tid >> 6;
  const int m0 = blockIdx.x * 128, n0 = blockIdx.y * 64;

  f32x4 acc[2][4];
  #pragma unroll
  for (int i = 0; i < 2; ++i)
    #pragma unroll
    for (int j = 0; j < 4; ++j)
      acc[i][j] = (f32x4){0.f,0.f,0.f,0.f};

  const int srow = tid >> 3, scol = (tid & 7) * 8;
  for (int kt = 0; kt < 512; kt += 64) {
    __syncthreads();
    #pragma unroll
    for (int it = 0; it < 4; ++it) {
      const int r = srow + it*32;
      *(s16x8*)&As[r][scol] = *(const s16x8*)&ABF[(size_t)(m0+r)*512 + kt + scol];
    }
    #pragma unroll
    for (int it = 0; it < 2; ++it) {
      const int r = srow + it*32;
      *(s16x8*)&Bs[r][scol] = *(const s16x8*)&WTC[(size_t)(n0+r)*512 + kt + scol];
    }
    __syncthreads();
    #pragma unroll
    for (int ks = 0; ks < 2; ++ks) {
      const int ko = ks*32 + (lane >> 4)*8;
      s16x8 af[2], bfr[4];
      #pragma unroll
      for (int i = 0; i < 2; ++i) af[i]  = *(const s16x8*)&As[wr*32 + i*16 + (lane & 15)][ko];
      #pragma unroll
      for (int j = 0; j < 4; ++j) bfr[j] = *(const s16x8*)&Bs[j*16 + (lane & 15)][ko];
      #pragma unroll
      for (int i = 0; i < 2; ++i)
        #pragma unroll
        for (int j = 0; j < 4; ++j)
          acc[i][j] = __builtin_amdgcn_mfma_f32_16x16x32_bf16(af[i], bfr[j], acc[i][j], 0, 0, 0);
    }
  }

  const float S2 = stats[2], S3 = stats[3], S4 = stats[4];
  #pragma unroll
  for (int i = 0; i < 2; ++i) {
    #pragma unroll
    for (int reg = 0; reg < 4; ++reg) {
      const int row = m0 + wr*32 + i*16 + ((lane >> 4) << 2) + reg;
      const float xv = x[row];
      const float rs = rsqrtf((xv*xv*S2 + 2.f*xv*S3 + S4)*(1.0f/NH) + 1e-5f);
      const float al = xv*rs, be = rs;
      #pragma unroll
      for (int j = 0; j < 4; ++j) {
        const int col = n0 + j*16 + (lane & 15);
        float v = acc[i][j][reg] + comb_b[col] + al*p2[col] + be*q2[col];
        A2[(size_t)row*1024 + col] = f2bf(fmaxf(v, 0.f));
      }
    }
  }
}

// ---------------------------------------------------------------------------
// kGRU: 64x128 tile, 4 waves (2x2), grid(32,16)=512 blocks = 2/CU.
// Each wave owns 32 rows x 64 cols = one gate-group g=(n0>>6)+wc; its 4
// j-frags are the 4 gates (t=j). Block-diagonal skip: j==2 (i_n) active only
// k<512, j==3 (h_n) only k>=512 -> 12 MFMAs per wave per K-step; inactive B
// rows ((r>>4)&3 == skipped t) not staged. Arithmetic intensity 2.4 MFMA/KB
// staged vs r12's 1.7 (A halves: 8 KB vs 16 KB per K-step).
// Epilogue: GRU gates -> h_new fp32 + fused out0 atomic reduce.
// ---------------------------------------------------------------------------
__global__ __launch_bounds__(256)
void kGRU(const ushort_t* __restrict__ A, const ushort_t* __restrict__ Bt,
          const float* __restrict__ bih, const float* __restrict__ bhh,
          const float* __restrict__ hidden, const float* __restrict__ out_W,
          float* __restrict__ h_out, float* __restrict__ out0)
{
  __shared__ ushort_t As[64][72];
  __shared__ ushort_t Bs[128][72];
  const int tid = threadIdx.x, lane = tid & 63, wv = tid >> 6;
  const int wr = wv >> 1, wc = wv & 1;
  const int m0 = blockIdx.x * 64, n0 = blockIdx.y * 128;

  f32x4 acc[2][4];
  #pragma unroll
  for (int i = 0; i < 2; ++i)
    #pragma unroll
    for (int j = 0; j < 4; ++j)
      acc[i][j] = (f32x4){0.f,0.f,0.f,0.f};

  const int srow = tid >> 3, scol = (tid & 7) * 8;

  // ---- K half 1: k in [0,512), active gates j = 0,1,2 (B rows t==3 zero)
  for (int kt = 0; kt < 512; kt += 64) {
    __syncthreads();
    #pragma unroll
    for (int it = 0; it < 2; ++it) {
      const int r = srow + it*32;
      *(s16x8*)&As[r][scol] = *(const s16x8*)&A[(size_t)(m0+r)*1024 + kt + scol];
    }
    #pragma unroll
    for (int it = 0; it < 4; ++it) {
      const int r = srow + it*32;
      if (((r >> 4) & 3) != 3)
        *(s16x8*)&Bs[r][scol] = *(const s16x8*)&Bt[(size_t)(n0+r)*1024 + kt + scol];
    }
    __syncthreads();
    #pragma unroll
    for (int ks = 0; ks < 2; ++ks) {
      const int ko = ks*32 + (lane >> 4)*8;
      s16x8 af[2], b0, b1, b2;
      #pragma unroll
      for (int i = 0; i < 2; ++i) af[i] = *(const s16x8*)&As[wr*32 + i*16 + (lane & 15)][ko];
      b0 = *(const s16x8*)&Bs[wc*64 + 0*16 + (lane & 15)][ko];
      b1 = *(const s16x8*)&Bs[wc*64 + 1*16 + (lane & 15)][ko];
      b2 = *(const s16x8*)&Bs[wc*64 + 2*16 + (lane & 15)][ko];
      #pragma unroll
      for (int i = 0; i < 2; ++i) {
        acc[i][0] = __builtin_amdgcn_mfma_f32_16x16x32_bf16(af[i], b0, acc[i][0], 0, 0, 0);
        acc[i][1] = __builtin_amdgcn_mfma_f32_16x16x32_bf16(af[i], b1, acc[i][1], 0, 0, 0);
        acc[i][2] = __builtin_amdgcn_mfma_f32_16x16x32_bf16(af[i], b2, acc[i][2], 0, 0, 0);
      }
    }
  }
  // ---- K half 2: k in [512,1024), active gates j = 0,1,3 (B rows t==2 zero)
  for (int kt = 512; kt < 1024; kt += 64) {
    __syncthreads();
    #pragma unroll
    for (int it = 0; it < 2; ++it) {
      const int r = srow + it*32;
      *(s16x8*)&As[r][scol] = *(const s16x8*)&A[(size_t)(m0+r)*1024 + kt + scol];
    }
    #pragma unroll
    for (int it = 0; it < 4; ++it) {
      const int r = srow + it*32;
      if (((r >> 4) & 3) != 2)
        *(s16x8*)&Bs[r][scol] = *(const s16x8*)&Bt[(size_t)(n0+r)*1024 + kt + scol];
    }
    __syncthreads();
    #pragma unroll
    for (int ks = 0; ks < 2; ++ks) {
      const int ko = ks*32 + (lane >> 4)*8;
      s16x8 af[2], b0, b1, b3;
      #pragma unroll
      for (int i = 0; i < 2; ++i) af[i] = *(const s16x8*)&As[wr*32 + i*16 + (lane & 15)][ko];
      b0 = *(const s16x8*)&Bs[wc*64 + 0*16 + (lane & 15)][ko];
      b1 = *(const s16x8*)&Bs[wc*64 + 1*16 + (lane & 15)][ko];
      b3 = *(const s16x8*)&Bs[wc*64 + 3*16 + (lane & 15)][ko];
      #pragma unroll
      for (int i = 0; i < 2; ++i) {
        acc[i][0] = __builtin_amdgcn_mfma_f32_16x16x32_bf16(af[i], b0, acc[i][0], 0, 0, 0);
        acc[i][1] = __builtin_amdgcn_mfma_f32_16x16x32_bf16(af[i], b1, acc[i][1], 0, 0, 0);
        acc[i][3] = __builtin_amdgcn_mfma_f32_16x16x32_bf16(af[i], b3, acc[i][3], 0, 0, 0);
      }
    }
  }

  const int g = (n0 >> 6) + wc;
  const int hcol = (g << 4) | (lane & 15);
  const float b_r = bih[hcol]        + bhh[hcol];
  const float b_z = bih[512 + hcol]  + bhh[512 + hcol];
  const float b_i = bih[1024 + hcol];
  const float b_h = bhh[1024 + hcol];
  const float ow  = out_W[hcol];
  #pragma unroll
  for (int i = 0; i < 2; ++i) {
    #pragma unroll
    for (int reg = 0; reg < 4; ++reg) {
      const int row = m0 + wr*32 + i*16 + ((lane >> 4) << 2) + reg;
      float rv = 1.f / (1.f + expf(-(acc[i][0][reg] + b_r)));
      float zv = 1.f / (1.f + expf(-(acc[i][1][reg] + b_z)));
      float nv = tanhf(acc[i][2][reg] + b_i + rv * (acc[i][3][reg] + b_h));
      float h0v = hidden[(size_t)row*NH + hcol];
      float hn = nv + zv * (h0v - nv);
      h_out[(size_t)row*NH + hcol] = hn;
      float partial = hn * ow;
      #pragma unroll
      for (int o = 1; o < 16; o <<= 1) partial += __shfl_xor(partial, o);
      if ((lane & 15) == 0) atomicAdd(&out0[row], partial);
    }
  }
}

// ---------------------------------------------------------------------------
extern "C" void kernel_launch(void* const* d_in, const int* in_sizes, int n_in,
                              void* d_out, int out_size, void* d_ws, size_t ws_size,
                              hipStream_t stream)
{
  const float* x      = (const float*)d_in[0];
  const float* hidden = (const float*)d_in[1];
  const float* enc    = (const float*)d_in[2];
  const float* emb_W  = (const float*)d_in[3];
  const float* emb_b  = (const float*)d_in[4];
  const float* attn_W = (const float*)d_in[5];
  const float* attn_b = (const float*)d_in[6];
  const float* comb_W = (const float*)d_in[7];
  const float* comb_b = (const float*)d_in[8];
  const float* Wih    = (const float*)d_in[9];
  const float* Whh    = (const float*)d_in[10];
  const float* bih    = (const float*)d_in[11];
  const float* bhh    = (const float*)d_in[12];
  const float* out_W  = (const float*)d_in[13];
  const float* out_b  = (const float*)d_in[14];

  float* out      = (float*)d_out;
  float* out0     = out;                          // 2048
  float* out_h    = out + NB;                     // B*H
  float* out_attn = out + NB + (size_t)NB*NH;     // B*L

  float* wsf    = (float*)d_ws;
  float* stats  = wsf;              // 16
  float* p      = wsf + 16;         // 256
  float* q      = wsf + 272;        // 256
  float* p2     = wsf + 528;        // 512
  float* q2     = wsf + 1040;       // 512
  float* logits = wsf + 2048;       // [2048][256] fp32
  ushort_t* usb = (ushort_t*)(wsf + 526400);
  ushort_t* A2  = usb;              // [2048][1024] bf16: [xt | h0]
  ushort_t* ABF = usb + 2097152;    // [2048][512]  bf16 attn_applied
  ushort_t* WTA = usb + 3145728;    // [256][512]
  ushort_t* WTC = usb + 3276800;    // [512][512]
  ushort_t* WTG = usb + 3538944;    // [2048][1024]

  kTiny<<<37, 256, 0, stream>>>(emb_W, emb_b, attn_W, WTA, stats, p, q);
  kLogits<<<dim3(16, 4), 256, 0, stream>>>(hidden, WTA, x, stats, p, q,
                                           attn_b, logits);
  kStreamMega<<<3152, 256, 0, stream>>>(hidden, Wih, Whh, comb_W, emb_W, emb_b,
                                        out_b, logits, enc, A2, WTG, WTC,
                                        p2, q2, out0, out_attn, ABF);
  kComb<<<dim3(16, 8), 256, 0, stream>>>(ABF, WTC, x, stats, p2, q2, comb_b, A2);
  kGRU<<<dim3(32, 16), 256, 0, stream>>>(A2, WTG, bih, bhh, hidden, out_W,
                                         out_h, out0);
}

// Round 15
// 246.444 us; speedup vs baseline: 1.4537x; 1.0748x over previous
//
#include <hip/hip_runtime.h>
#include <math.h>

#define NB 2048
#define NL 256
#define NH 512

typedef unsigned short ushort_t;
typedef unsigned int uint_t;
typedef short s16x8 __attribute__((ext_vector_type(8)));
typedef short s16x4 __attribute__((ext_vector_type(4)));
typedef float f32x4 __attribute__((ext_vector_type(4)));

__device__ __forceinline__ float wsum(float v){
  #pragma unroll
  for (int o = 32; o; o >>= 1) v += __shfl_xor(v, o);
  return v;
}
__device__ __forceinline__ float wmax(float v){
  #pragma unroll
  for (int o = 32; o; o >>= 1) v = fmaxf(v, __shfl_xor(v, o));
  return v;
}
__device__ __forceinline__ ushort_t f2bf(float f){
  union { float f; unsigned u; } v; v.f = f;
  unsigned r = v.u + 0x7fffu + ((v.u >> 16) & 1u);
  return (ushort_t)(r >> 16);
}

// ---------------------------------------------------------------------------
// kTiny (37 blocks x 256): minimal pre-logits prep.
//  bid < 32: WTA[c][k] = bf16 attn_W_bottom^T  (256x512)
//  bid < 36: p,q (attn top rank-2)
//  bid ==36: stats = {mW, mb, Su2, Suv, Sv2}
// (p2/q2 + out0-init live in kStreamMega tail — consumed only by kComb/kGRU)
// ---------------------------------------------------------------------------
__global__ __launch_bounds__(256)
void kTiny(const float* __restrict__ eW, const float* __restrict__ eb,
           const float* __restrict__ attn_W,
           ushort_t* __restrict__ WTA, float* __restrict__ stats,
           float* __restrict__ p, float* __restrict__ q)
{
  const int bid = blockIdx.x, tid = threadIdx.x;
  if (bid < 32) {                        // WTA bf16 transpose
    const int bx = bid & 3, by = bid >> 2;
    const int c = bx*64 + (tid & 63);
    const int ksub = by*64 + (tid >> 6)*16;
    ushort_t vals[16];
    #pragma unroll
    for (int kk = 0; kk < 16; ++kk)
      vals[kk] = f2bf(attn_W[(size_t)(512 + ksub + kk)*NL + c]);
    *(s16x8*)&WTA[(size_t)c*512 + ksub]     = *(s16x8*)&vals[0];
    *(s16x8*)&WTA[(size_t)c*512 + ksub + 8] = *(s16x8*)&vals[8];
    return;
  }
  // rank-2 projections + stats
  {
    __shared__ float rw[4], rb[4];
    __shared__ float pa[4][64], pb[4][64];
    const int lane = tid & 63, wv = tid >> 6;
    float swv = eW[tid] + eW[tid + 256];
    float sbv = eb[tid] + eb[tid + 256];
    swv = wsum(swv); sbv = wsum(sbv);
    if (lane == 0) { rw[wv] = swv; rb[wv] = sbv; }
    __syncthreads();
    const float mW = (rw[0]+rw[1]+rw[2]+rw[3]) * (1.f/NH);
    const float mb = (rb[0]+rb[1]+rb[2]+rb[3]) * (1.f/NH);

    if (bid == 36) {
      float u0 = eW[tid]-mW, u1 = eW[tid+256]-mW;
      float v0 = eb[tid]-mb, v1 = eb[tid+256]-mb;
      float s2 = u0*u0 + u1*u1, s3 = u0*v0 + u1*v1, s4 = v0*v0 + v1*v1;
      s2 = wsum(s2); s3 = wsum(s3); s4 = wsum(s4);
      if (lane == 0) { pa[0][wv] = s2; pa[1][wv] = s3; pa[2][wv] = s4; }
      __syncthreads();
      if (tid == 0) {
        stats[0] = mW; stats[1] = mb;
        stats[2] = pa[0][0]+pa[0][1]+pa[0][2]+pa[0][3];
        stats[3] = pa[1][0]+pa[1][1]+pa[1][2]+pa[1][3];
        stats[4] = pa[2][0]+pa[2][1]+pa[2][2]+pa[2][3];
      }
      return;
    }
    const int c = (bid - 32)*64 + lane;
    const int hc = tid >> 6;
    float ap = 0.f, aq = 0.f;
    #pragma unroll 4
    for (int h = hc*128; h < hc*128 + 128; ++h) {
      float w = attn_W[(size_t)h*NL + c];
      ap = fmaf(eW[h]-mW, w, ap);
      aq = fmaf(eb[h]-mb, w, aq);
    }
    pa[hc][lane] = ap; pb[hc][lane] = aq;
    __syncthreads();
    if (hc == 0) {
      p[c] = pa[0][lane]+pa[1][lane]+pa[2][lane]+pa[3][lane];
      q[c] = pb[0][lane]+pb[1][lane]+pb[2][lane]+pb[3][lane];
    }
  }
}

// ---------------------------------------------------------------------------
// kLogits: 128x64 tile MFMA GEMM, A staged DIRECTLY from fp32 hidden
// (cvt during staging). B = WTA bf16. Epilogue: logits = acc + attn_b + rank2
// -> fp32 [2048][256]. grid(16,4).
// ---------------------------------------------------------------------------
__global__ __launch_bounds__(256)
void kLogits(const float* __restrict__ hidden, const ushort_t* __restrict__ WTA,
             const float* __restrict__ x, const float* __restrict__ stats,
             const float* __restrict__ p, const float* __restrict__ q,
             const float* __restrict__ attn_b, float* __restrict__ logits)
{
  __shared__ ushort_t As[128][72];
  __shared__ ushort_t Bs[64][72];
  const int tid = threadIdx.x, lane = tid & 63, wr = tid >> 6;
  const int m0 = blockIdx.x * 128, n0 = blockIdx.y * 64;

  f32x4 acc[2][4];
  #pragma unroll
  for (int i = 0; i < 2; ++i)
    #pragma unroll
    for (int j = 0; j < 4; ++j)
      acc[i][j] = (f32x4){0.f,0.f,0.f,0.f};

  const int srow = tid >> 3, scol = (tid & 7) * 8;
  for (int kt = 0; kt < 512; kt += 64) {
    __syncthreads();
    #pragma unroll
    for (int it = 0; it < 4; ++it) {
      const int r = srow + it*32;
      const float* hp = hidden + (size_t)(m0+r)*NH + kt + scol;
      float4 v0 = *(const float4*)hp;
      float4 v1 = *(const float4*)(hp + 4);
      s16x8 o;
      o[0]=f2bf(v0.x); o[1]=f2bf(v0.y); o[2]=f2bf(v0.z); o[3]=f2bf(v0.w);
      o[4]=f2bf(v1.x); o[5]=f2bf(v1.y); o[6]=f2bf(v1.z); o[7]=f2bf(v1.w);
      *(s16x8*)&As[r][scol] = o;
    }
    #pragma unroll
    for (int it = 0; it < 2; ++it) {
      const int r = srow + it*32;
      *(s16x8*)&Bs[r][scol] = *(const s16x8*)&WTA[(size_t)(n0+r)*512 + kt + scol];
    }
    __syncthreads();
    #pragma unroll
    for (int ks = 0; ks < 2; ++ks) {
      const int ko = ks*32 + (lane >> 4)*8;
      s16x8 af[2], bfr[4];
      #pragma unroll
      for (int i = 0; i < 2; ++i) af[i]  = *(const s16x8*)&As[wr*32 + i*16 + (lane & 15)][ko];
      #pragma unroll
      for (int j = 0; j < 4; ++j) bfr[j] = *(const s16x8*)&Bs[j*16 + (lane & 15)][ko];
      #pragma unroll
      for (int i = 0; i < 2; ++i)
        #pragma unroll
        for (int j = 0; j < 4; ++j)
          acc[i][j] = __builtin_amdgcn_mfma_f32_16x16x32_bf16(af[i], bfr[j], acc[i][j], 0, 0, 0);
    }
  }

  const float S2 = stats[2], S3 = stats[3], S4 = stats[4];
  #pragma unroll
  for (int i = 0; i < 2; ++i) {
    #pragma unroll
    for (int reg = 0; reg < 4; ++reg) {
      const int row = m0 + wr*32 + i*16 + ((lane >> 4) << 2) + reg;
      const float xv = x[row];
      const float rs = rsqrtf((xv*xv*S2 + 2.f*xv*S3 + S4)*(1.0f/NH) + 1e-5f);
      const float al = xv*rs, be = rs;
      #pragma unroll
      for (int j = 0; j < 4; ++j) {
        const int col = n0 + j*16 + (lane & 15);
        logits[(size_t)row*NL + col] = acc[i][j][reg] + attn_b[col] + al*p[col] + be*q[col];
      }
    }
  }
}

// ---------------------------------------------------------------------------
// kStreamMega (3152 blocks x 256): STREAM BLOCKS FIRST (bid < 2048); prep
// blocks dispatch into the stream's spare slots as stream blocks retire.
//  bid < 2048: softmax(logits[b]) -> attn_out + wl; a = sum_l wl*enc -> ABF
//  bid < 2560: hidden fp32 -> bf16 into A2 right half (lda 1024)
//  bid < 3072: WTG[n][k] bf16 gate-interleaved blockdiag GRU weight
//  bid < 3136: WTC[c][k] = bf16 comb_W_bottom^T (512x512)
//  bid < 3144: p2,q2 (comb top rank-2)
//  else      : out0[b] = out_b[0]
// ---------------------------------------------------------------------------
__global__ __launch_bounds__(256)
void kStreamMega(const float* __restrict__ hidden,
                 const float* __restrict__ Wih, const float* __restrict__ Whh,
                 const float* __restrict__ comb_W,
                 const float* __restrict__ eW, const float* __restrict__ eb,
                 const float* __restrict__ out_b,
                 const float* __restrict__ logits, const float* __restrict__ enc,
                 ushort_t* __restrict__ A2, ushort_t* __restrict__ WTG,
                 ushort_t* __restrict__ WTC,
                 float* __restrict__ p2, float* __restrict__ q2,
                 float* __restrict__ out0,
                 float* __restrict__ attn_out, ushort_t* __restrict__ ABF)
{
  const int bid = blockIdx.x, tid = threadIdx.x;
  if (bid < 2048) {                      // ---- stream block
    __shared__ float wl[NL];
    __shared__ __align__(16) float4 ps[128];
    __shared__ float sred[4];
    const int lane = tid & 63, wv = tid >> 6;
    const int b = bid;

    float lg = logits[(size_t)b*NL + tid];
    float m = wmax(lg);
    if (lane == 0) sred[wv] = m;
    __syncthreads();
    m = fmaxf(fmaxf(sred[0], sred[1]), fmaxf(sred[2], sred[3]));
    float e = expf(lg - m);
    float s = wsum(e);
    __syncthreads();
    if (lane == 0) sred[wv] = s;
    __syncthreads();
    const float inv = 1.f / (sred[0] + sred[1] + sred[2] + sred[3]);
    e *= inv;
    wl[tid] = e;
    attn_out[(size_t)b*NL + tid] = e;
    __syncthreads();

    const int col = tid & 127, half = tid >> 7;
    const f32x4* ep = (const f32x4*)(enc + (size_t)b*NL*NH);
    float4 acc = {0.f,0.f,0.f,0.f};
    #pragma unroll 4
    for (int l = half*128; l < half*128 + 128; ++l) {
      float w = wl[l];
      f32x4 ev = __builtin_nontemporal_load(ep + l*(NH/4) + col);
      acc.x = fmaf(w,ev[0],acc.x); acc.y = fmaf(w,ev[1],acc.y);
      acc.z = fmaf(w,ev[2],acc.z); acc.w = fmaf(w,ev[3],acc.w);
    }
    if (half == 0) ps[col] = acc;
    __syncthreads();
    if (half == 1) {
      float4 o = ps[col];
      o.x += acc.x; o.y += acc.y; o.z += acc.z; o.w += acc.w;
      s16x4 ov; ov[0]=f2bf(o.x); ov[1]=f2bf(o.y); ov[2]=f2bf(o.z); ov[3]=f2bf(o.w);
      *(s16x4*)&ABF[(size_t)b*NH + col*4] = ov;
    }
    return;
  }
  if (bid < 2560) {                      // hidden -> bf16 A2 right half
    const int idx = ((bid-2048)*256 + tid) * 8;
    const int b = idx >> 9, h = idx & 511;
    float4 v0 = *(const float4*)(hidden + idx);
    float4 v1 = *(const float4*)(hidden + idx + 4);
    s16x8 o;
    o[0]=f2bf(v0.x); o[1]=f2bf(v0.y); o[2]=f2bf(v0.z); o[3]=f2bf(v0.w);
    o[4]=f2bf(v1.x); o[5]=f2bf(v1.y); o[6]=f2bf(v1.z); o[7]=f2bf(v1.w);
    *(s16x8*)&A2[(size_t)b*1024 + 512 + h] = o;
    return;
  }
  if (bid < 3072) {                      // WTG bf16 gate-blockdiag
    const int b2 = bid - 2560, bx = b2 & 31, by = b2 >> 5;
    const int n = bx*64 + (tid & 63);
    const int ksub = by*64 + (tid >> 6)*16;
    const int g = n >> 6, t = (n >> 4) & 3, c = (g << 4) | (n & 15);
    const int sc = (t == 0) ? c : (t == 1) ? (512 + c) : (1024 + c);
    ushort_t vals[16];
    #pragma unroll
    for (int kk = 0; kk < 16; ++kk) {
      int k = ksub + kk;
      float v;
      if (k < 512) v = (t == 3) ? 0.f : Wih[(size_t)k*1536 + sc];
      else         v = (t == 2) ? 0.f : Whh[(size_t)(k-512)*1536 + sc];
      vals[kk] = f2bf(v);
    }
    *(s16x8*)&WTG[(size_t)n*1024 + ksub]     = *(s16x8*)&vals[0];
    *(s16x8*)&WTG[(size_t)n*1024 + ksub + 8] = *(s16x8*)&vals[8];
    return;
  }
  if (bid < 3136) {                      // WTC bf16 transpose
    const int b2 = bid - 3072, bx = b2 & 7, by = b2 >> 3;
    const int c = bx*64 + (tid & 63);
    const int ksub = by*64 + (tid >> 6)*16;
    ushort_t vals[16];
    #pragma unroll
    for (int kk = 0; kk < 16; ++kk)
      vals[kk] = f2bf(comb_W[(size_t)(512 + ksub + kk)*NH + c]);
    *(s16x8*)&WTC[(size_t)c*512 + ksub]     = *(s16x8*)&vals[0];
    *(s16x8*)&WTC[(size_t)c*512 + ksub + 8] = *(s16x8*)&vals[8];
    return;
  }
  if (bid < 3144) {                      // p2,q2 (comb top rank-2)
    __shared__ float rw[4], rb[4];
    __shared__ float pa[4][64], pb[4][64];
    const int lane = tid & 63, wv = tid >> 6;
    float swv = eW[tid] + eW[tid + 256];
    float sbv = eb[tid] + eb[tid + 256];
    swv = wsum(swv); sbv = wsum(sbv);
    if (lane == 0) { rw[wv] = swv; rb[wv] = sbv; }
    __syncthreads();
    const float mW = (rw[0]+rw[1]+rw[2]+rw[3]) * (1.f/NH);
    const float mb = (rb[0]+rb[1]+rb[2]+rb[3]) * (1.f/NH);
    const int c = (bid - 3136)*64 + lane;
    const int hc = tid >> 6;
    float ap = 0.f, aq = 0.f;
    #pragma unroll 4
    for (int h = hc*128; h < hc*128 + 128; ++h) {
      float w = comb_W[(size_t)h*NH + c];
      ap = fmaf(eW[h]-mW, w, ap);
      aq = fmaf(eb[h]-mb, w, aq);
    }
    pa[hc][lane] = ap; pb[hc][lane] = aq;
    __syncthreads();
    if (hc == 0) {
      p2[c] = pa[0][lane]+pa[1][lane]+pa[2][lane]+pa[3][lane];
      q2[c] = pb[0][lane]+pb[1][lane]+pb[2][lane]+pb[3][lane];
    }
    return;
  }
  out0[(bid-3144)*256 + tid] = out_b[0]; // out0 init
}

// ---------------------------------------------------------------------------
// kComb: 128x64 tile. xt = relu(ABF @ WTC^T + comb_b + rank2) -> bf16 A2 left
// (ld 1024). grid(16,8).
// ---------------------------------------------------------------------------
__global__ __launch_bounds__(256)
void kComb(const ushort_t* __restrict__ ABF, const ushort_t* __restrict__ WTC,
           const float* __restrict__ x, const float* __restrict__ stats,
           const float* __restrict__ p2, const float* __restrict__ q2,
           const float* __restrict__ comb_b, ushort_t* __restrict__ A2)
{
  __shared__ ushort_t As[128][72];
  __shared__ ushort_t Bs[64][72];
  const int tid = threadIdx.x, lane = tid & 63, wr = tid >> 6;
  const int m0 = blockIdx.x * 128, n0 = blockIdx.y * 64;

  f32x4 acc[2][4];
  #pragma unroll
  for (int i = 0; i < 2; ++i)
    #pragma unroll
    for (int j = 0; j < 4; ++j)
      acc[i][j] = (f32x4){0.f,0.f,0.f,0.f};

  const int srow = tid >> 3, scol = (tid & 7) * 8;
  for (int kt = 0; kt < 512; kt += 64) {
    __syncthreads();
    #pragma unroll
    for (int it = 0; it < 4; ++it) {
      const int r = srow + it*32;
      *(s16x8*)&As[r][scol] = *(const s16x8*)&ABF[(size_t)(m0+r)*512 + kt + scol];
    }
    #pragma unroll
    for (int it = 0; it < 2; ++it) {
      const int r = srow + it*32;
      *(s16x8*)&Bs[r][scol] = *(const s16x8*)&WTC[(size_t)(n0+r)*512 + kt + scol];
    }
    __syncthreads();
    #pragma unroll
    for (int ks = 0; ks < 2; ++ks) {
      const int ko = ks*32 + (lane >> 4)*8;
      s16x8 af[2], bfr[4];
      #pragma unroll
      for (int i = 0; i < 2; ++i) af[i]  = *(const s16x8*)&As[wr*32 + i*16 + (lane & 15)][ko];
      #pragma unroll
      for (int j = 0; j < 4; ++j) bfr[j] = *(const s16x8*)&Bs[j*16 + (lane & 15)][ko];
      #pragma unroll
      for (int i = 0; i < 2; ++i)
        #pragma unroll
        for (int j = 0; j < 4; ++j)
          acc[i][j] = __builtin_amdgcn_mfma_f32_16x16x32_bf16(af[i], bfr[j], acc[i][j], 0, 0, 0);
    }
  }

  const float S2 = stats[2], S3 = stats[3], S4 = stats[4];
  #pragma unroll
  for (int i = 0; i < 2; ++i) {
    #pragma unroll
    for (int reg = 0; reg < 4; ++reg) {
      const int row = m0 + wr*32 + i*16 + ((lane >> 4) << 2) + reg;
      const float xv = x[row];
      const float rs = rsqrtf((xv*xv*S2 + 2.f*xv*S3 + S4)*(1.0f/NH) + 1e-5f);
      const float al = xv*rs, be = rs;
      #pragma unroll
      for (int j = 0; j < 4; ++j) {
        const int col = n0 + j*16 + (lane & 15);
        float v = acc[i][j][reg] + comb_b[col] + al*p2[col] + be*q2[col];
        A2[(size_t)row*1024 + col] = f2bf(fmaxf(v, 0.f));
      }
    }
  }
}

// ---------------------------------------------------------------------------
// kGRU: 128x64 tile, 4 waves (4x1), 512 blocks = 2/CU. A = [xt|h0] bf16
// (lda 1024), Bt = WTG (2048x1024). Block-diagonal skip: gate j==2 (i_n)
// only has nonzero B for k<512; j==3 (h_n) only for k>=512 — the K-loop is
// split into two static halves doing 12 MFMAs/K-step instead of 16, and the
// zero B rows are not staged. Epilogue: GRU gates -> h_new fp32 + fused out0
// atomic reduce (out0 pre-init to out_b in kStreamMega).
// ---------------------------------------------------------------------------
__global__ __launch_bounds__(256)
void kGRU(const ushort_t* __restrict__ A, const ushort_t* __restrict__ Bt,
          const float* __restrict__ bih, const float* __restrict__ bhh,
          const float* __restrict__ hidden, const float* __restrict__ out_W,
          float* __restrict__ h_out, float* __restrict__ out0)
{
  __shared__ ushort_t As[128][72];
  __shared__ ushort_t Bs[64][72];
  const int tid = threadIdx.x, lane = tid & 63, wr = tid >> 6;
  const int m0 = blockIdx.x * 128, n0 = blockIdx.y * 64;

  f32x4 acc[2][4];
  #pragma unroll
  for (int i = 0; i < 2; ++i)
    #pragma unroll
    for (int j = 0; j < 4; ++j)
      acc[i][j] = (f32x4){0.f,0.f,0.f,0.f};

  const int srow = tid >> 3, scol = (tid & 7) * 8;

  // ---- K half 1: k in [0,512), active gates j = 0,1,2 (B rows t==3 zero)
  for (int kt = 0; kt < 512; kt += 64) {
    __syncthreads();
    #pragma unroll
    for (int it = 0; it < 4; ++it) {
      const int r = srow + it*32;
      *(s16x8*)&As[r][scol] = *(const s16x8*)&A[(size_t)(m0+r)*1024 + kt + scol];
    }
    {
      *(s16x8*)&Bs[srow][scol] = *(const s16x8*)&Bt[(size_t)(n0+srow)*1024 + kt + scol];
      if (srow < 16) {
        const int r = srow + 32;
        *(s16x8*)&Bs[r][scol] = *(const s16x8*)&Bt[(size_t)(n0+r)*1024 + kt + scol];
      }
    }
    __syncthreads();
    #pragma unroll
    for (int ks = 0; ks < 2; ++ks) {
      const int ko = ks*32 + (lane >> 4)*8;
      s16x8 af[2], b0, b1, b2;
      #pragma unroll
      for (int i = 0; i < 2; ++i) af[i] = *(const s16x8*)&As[wr*32 + i*16 + (lane & 15)][ko];
      b0 = *(const s16x8*)&Bs[0*16 + (lane & 15)][ko];
      b1 = *(const s16x8*)&Bs[1*16 + (lane & 15)][ko];
      b2 = *(const s16x8*)&Bs[2*16 + (lane & 15)][ko];
      #pragma unroll
      for (int i = 0; i < 2; ++i) {
        acc[i][0] = __builtin_amdgcn_mfma_f32_16x16x32_bf16(af[i], b0, acc[i][0], 0, 0, 0);
        acc[i][1] = __builtin_amdgcn_mfma_f32_16x16x32_bf16(af[i], b1, acc[i][1], 0, 0, 0);
        acc[i][2] = __builtin_amdgcn_mfma_f32_16x16x32_bf16(af[i], b2, acc[i][2], 0, 0, 0);
      }
    }
  }
  // ---- K half 2: k in [512,1024), active gates j = 0,1,3 (B rows t==2 zero)
  for (int kt = 512; kt < 1024; kt += 64) {
    __syncthreads();
    #pragma unroll
    for (int it = 0; it < 4; ++it) {
      const int r = srow + it*32;
      *(s16x8*)&As[r][scol] = *(const s16x8*)&A[(size_t)(m0+r)*1024 + kt + scol];
    }
    {
      *(s16x8*)&Bs[srow][scol] = *(const s16x8*)&Bt[(size_t)(n0+srow)*1024 + kt + scol];
      if (srow >= 16) {
        const int r = srow + 32;
        *(s16x8*)&Bs[r][scol] = *(const s16x8*)&Bt[(size_t)(n0+r)*1024 + kt + scol];
      }
    }
    __syncthreads();
    #pragma unroll
    for (int ks = 0; ks < 2; ++ks) {
      const int ko = ks*32 + (lane >> 4)*8;
      s16x8 af[2], b0, b1, b3;
      #pragma unroll
      for (int i = 0; i < 2; ++i) af[i] = *(const s16x8*)&As[wr*32 + i*16 + (lane & 15)][ko];
      b0 = *(const s16x8*)&Bs[0*16 + (lane & 15)][ko];
      b1 = *(const s16x8*)&Bs[1*16 + (lane & 15)][ko];
      b3 = *(const s16x8*)&Bs[3*16 + (lane & 15)][ko];
      #pragma unroll
      for (int i = 0; i < 2; ++i) {
        acc[i][0] = __builtin_amdgcn_mfma_f32_16x16x32_bf16(af[i], b0, acc[i][0], 0, 0, 0);
        acc[i][1] = __builtin_amdgcn_mfma_f32_16x16x32_bf16(af[i], b1, acc[i][1], 0, 0, 0);
        acc[i][3] = __builtin_amdgcn_mfma_f32_16x16x32_bf16(af[i], b3, acc[i][3], 0, 0, 0);
      }
    }
  }

  const int g = n0 >> 6;
  const int hcol = (g << 4) | (lane & 15);
  const float b_r = bih[hcol]        + bhh[hcol];
  const float b_z = bih[512 + hcol]  + bhh[512 + hcol];
  const float b_i = bih[1024 + hcol];
  const float b_h = bhh[1024 + hcol];
  const float ow  = out_W[hcol];
  #pragma unroll
  for (int i = 0; i < 2; ++i) {
    #pragma unroll
    for (int reg = 0; reg < 4; ++reg) {
      const int row = m0 + wr*32 + i*16 + ((lane >> 4) << 2) + reg;
      float rv = 1.f / (1.f + expf(-(acc[i][0][reg] + b_r)));
      float zv = 1.f / (1.f + expf(-(acc[i][1][reg] + b_z)));
      float nv = tanhf(acc[i][2][reg] + b_i + rv * (acc[i][3][reg] + b_h));
      float h0v = hidden[(size_t)row*NH + hcol];
      float hn = nv + zv * (h0v - nv);
      h_out[(size_t)row*NH + hcol] = hn;
      float partial = hn * ow;
      #pragma unroll
      for (int o = 1; o < 16; o <<= 1) partial += __shfl_xor(partial, o);
      if ((lane & 15) == 0) atomicAdd(&out0[row], partial);
    }
  }
}

// ---------------------------------------------------------------------------
extern "C" void kernel_launch(void* const* d_in, const int* in_sizes, int n_in,
                              void* d_out, int out_size, void* d_ws, size_t ws_size,
                              hipStream_t stream)
{
  const float* x      = (const float*)d_in[0];
  const float* hidden = (const float*)d_in[1];
  const float* enc    = (const float*)d_in[2];
  const float* emb_W  = (const float*)d_in[3];
  const float* emb_b  = (const float*)d_in[4];
  const float* attn_W = (const float*)d_in[5];
  const float* attn_b = (const float*)d_in[6];
  const float* comb_W = (const float*)d_in[7];
  const float* comb_b = (const float*)d_in[8];
  const float* Wih    = (const float*)d_in[9];
  const float* Whh    = (const float*)d_in[10];
  const float* bih    = (const float*)d_in[11];
  const float* bhh    = (const float*)d_in[12];
  const float* out_W  = (const float*)d_in[13];
  const float* out_b  = (const float*)d_in[14];

  float* out      = (float*)d_out;
  float* out0     = out;                          // 2048
  float* out_h    = out + NB;                     // B*H
  float* out_attn = out + NB + (size_t)NB*NH;     // B*L

  float* wsf    = (float*)d_ws;
  float* stats  = wsf;              // 16
  float* p      = wsf + 16;         // 256
  float* q      = wsf + 272;        // 256
  float* p2     = wsf + 528;        // 512
  float* q2     = wsf + 1040;       // 512
  float* logits = wsf + 2048;       // [2048][256] fp32
  ushort_t* usb = (ushort_t*)(wsf + 526400);
  ushort_t* A2  = usb;              // [2048][1024] bf16: [xt | h0]
  ushort_t* ABF = usb + 2097152;    // [2048][512]  bf16 attn_applied
  ushort_t* WTA = usb + 3145728;    // [256][512]
  ushort_t* WTC = usb + 3276800;    // [512][512]
  ushort_t* WTG = usb + 3538944;    // [2048][1024]

  kTiny<<<37, 256, 0, stream>>>(emb_W, emb_b, attn_W, WTA, stats, p, q);
  kLogits<<<dim3(16, 4), 256, 0, stream>>>(hidden, WTA, x, stats, p, q,
                                           attn_b, logits);
  kStreamMega<<<3152, 256, 0, stream>>>(hidden, Wih, Whh, comb_W, emb_W, emb_b,
                                        out_b, logits, enc, A2, WTG, WTC,
                                        p2, q2, out0, out_attn, ABF);
  kComb<<<dim3(16, 8), 256, 0, stream>>>(ABF, WTC, x, stats, p2, q2, comb_b, A2);
  kGRU<<<dim3(16, 32), 256, 0, stream>>>(A2, WTG, bih, bhh, hidden, out_W,
                                         out_h, out0);
}